// Round 9
// baseline (439.502 us; speedup 1.0000x reference)
//
#include <hip/hip_runtime.h>
#include <hip/hip_bf16.h>
#include <hip/hip_cooperative_groups.h>

namespace cg = cooperative_groups;

#define S_ 64
#define P_ 32
#define N_ 2048
#define H_ 64
#define E_ 64
#define D1_ 512
#define D2_ 1024
#define EPS_ 1e-5f

typedef unsigned short u16;
using bf16x8 = __attribute__((ext_vector_type(8))) __bf16;
using floatx4 = __attribute__((ext_vector_type(4))) float;

__device__ inline u16 f2bf(float x) {
    unsigned u = __float_as_uint(x);
    unsigned r = (u + 0x7fffu + ((u >> 16) & 1u)) >> 16;
    return (u16)r;
}
__device__ inline unsigned bf2pack(float lo, float hi) {
    return (unsigned)f2bf(lo) | ((unsigned)f2bf(hi) << 16);
}

// ============================================================================
// Shared device helpers (used by both coop and fallback paths)
// ============================================================================

// Scene prep for one (scene, d-quarter), 256 threads. Writes BN1'd A/B factors.
__device__ void prep_scene_256(int u, int tid, float* smem,
                               const float* __restrict__ pos, const float* __restrict__ h,
                               const float* __restrict__ We, const float* __restrict__ W1,
                               const float* __restrict__ g1, const float* __restrict__ be1,
                               float* __restrict__ A, float* __restrict__ Bv) {
    const int s = u >> 2, dq = u & 3;
    const int jg = tid >> 7, dl = tid & 127;   // 2 j-groups x 128 channels
    const int d = (dq << 7) + dl;
    float* hs = smem;           // 2048: h[j][e]
    float* ps = smem + 2048;    // 64: pos
    float* red = smem + 2112;   // 1024: 4 stats x 256 threads
    for (int i = tid; i < 2048; i += 256) hs[i] = h[(size_t)s * 2048 + i];
    if (tid < 64) ps[tid] = pos[s * 64 + tid];
    __syncthreads();
    float wq0 = 0.f, wq1 = 0.f;
    for (int e = 0; e < 64; ++e) {
        const float wv = W1[e * 512 + d];
        wq0 += We[e] * wv;
        wq1 += We[64 + e] * wv;
    }
    float w[16], uu[16];
#pragma unroll
    for (int jj = 0; jj < 16; ++jj) w[jj] = 0.f;
    const float4* h4 = (const float4*)hs;
    for (int e4 = 0; e4 < 16; ++e4) {
        const float c0 = W1[(64 + e4 * 4 + 0) * 512 + d];
        const float c1 = W1[(64 + e4 * 4 + 1) * 512 + d];
        const float c2 = W1[(64 + e4 * 4 + 2) * 512 + d];
        const float c3 = W1[(64 + e4 * 4 + 3) * 512 + d];
#pragma unroll
        for (int jj = 0; jj < 16; ++jj) {
            const float4 hv = h4[((jg << 4) + jj) * 16 + e4];
            w[jj] += hv.x * c0 + hv.y * c1 + hv.z * c2 + hv.w * c3;
        }
    }
    float sw = 0.f, sww = 0.f, su = 0.f, suu = 0.f;
#pragma unroll
    for (int jj = 0; jj < 16; ++jj) {
        const int j = (jg << 4) + jj;
        uu[jj] = ps[2 * j] * wq0 + ps[2 * j + 1] * wq1;
        w[jj] += uu[jj];
        sw += w[jj]; sww += w[jj] * w[jj];
        su += uu[jj]; suu += uu[jj] * uu[jj];
    }
    red[(jg << 7) + dl] = sw;
    red[256 + (jg << 7) + dl] = sww;
    red[512 + (jg << 7) + dl] = su;
    red[768 + (jg << 7) + dl] = suu;
    __syncthreads();
    const float tw = red[dl] + red[128 + dl];
    const float tww = red[256 + dl] + red[384 + dl];
    const float tu = red[512 + dl] + red[640 + dl];
    const float tuu = red[768 + dl] + red[896 + dl];
    const float mw = tw * (1.f / 32.f), mu2 = tu * (1.f / 32.f);
    const float var = (tww * (1.f / 32.f) - mw * mw) + (tuu * (1.f / 32.f) - mu2 * mu2);
    const float sc = rsqrtf(var + EPS_) * g1[d];
    const float bb = be1[d];
#pragma unroll
    for (int jj = 0; jj < 16; ++jj) {
        const int j = (jg << 4) + jj;
        A[(size_t)(s * 32 + j) * 512 + d] = (w[jj] - mw) * sc + bb;
        Bv[(size_t)(s * 32 + j) * 512 + d] = (uu[jj] - mu2) * sc;
    }
}

// W2 transpose+bf16 for one 64x64 tile, 256 threads.
__device__ void w2t_tile_256(int b2, int tid, void* smem,
                             const float* __restrict__ W2, u16* __restrict__ w2t) {
    float (*tile)[65] = (float (*)[65])smem;  // 16.6 KB
    const int bi = b2 & 15, bj = b2 >> 4;     // 16 n-tiles x 8 k-tiles
    const int tx = tid & 63, ty = tid >> 6;   // 64 x 4
#pragma unroll
    for (int i = 0; i < 64; i += 4)
        tile[ty + i][tx] = W2[(size_t)(bj * 64 + ty + i) * 1024 + bi * 64 + tx];
    __syncthreads();
#pragma unroll
    for (int i = 0; i < 64; i += 4)
        w2t[(size_t)(bi * 64 + ty + i) * 512 + bj * 64 + tx] = f2bf(tile[tx][ty + i]);
}

// R5-proven fused GEMM body for one M-tile (128 rows = 4 peds x 32 j),
// 4 col-splits of 256. 256 threads. As 16 KB + Ws 32 KB LDS.
__device__ void gemm_mtile(int mt, int tid, u16* As, u16* Ws,
                           const float* __restrict__ A, const float* __restrict__ Bv,
                           const u16* __restrict__ w2t,
                           float* __restrict__ maxv, float* __restrict__ minv,
                           float* __restrict__ psum, float* __restrict__ psumsq) {
    const int wave = tid >> 6, lane = tid & 63;
    const int wm = wave >> 1, wn = wave & 1;
    const int quad = lane >> 4, l16 = lane & 15;
    const int lrow = lane >> 3, lchk = lane & 7;
    const int gchk = lchk ^ lrow;
    const int sj = tid >> 3, sc8 = tid & 7;
    const int s2 = mt >> 3, rb = mt & 7;
    const int pedb = rb << 2;
    const float* Aj = A + ((size_t)(s2 * 32 + sj) << 9) + (sc8 << 3);
    const float* Bp = Bv + ((size_t)(s2 * 32 + pedb) << 9) + (sc8 << 3);
    const int swz = (sc8 ^ (sj & 7)) << 3;

    for (int cs = 0; cs < 4; ++cs) {
        const int N0 = cs << 8;
        floatx4 acc[4][8] = {};
        for (int it = 0; it < 8; ++it) {
            const int k0 = it << 6;
#pragma unroll
            for (int t = 0; t < 8; ++t) {
                const int rbase = (wave << 6) + (t << 3);
                const u16* gb = w2t + (size_t)(N0 + rbase + lrow) * 512 + (k0 + (gchk << 3));
                __builtin_amdgcn_global_load_lds(
                    (const __attribute__((address_space(1))) void*)gb,
                    (__attribute__((address_space(3))) void*)(Ws + (rbase << 6)), 16, 0, 0);
            }
#pragma unroll
            for (int p = 0; p < 4; ++p) {
                const int r = (p << 5) + sj;
                const float4 alo = *(const float4*)(Aj + k0);
                const float4 ahi = *(const float4*)(Aj + k0 + 4);
                const float4 blo = *(const float4*)(Bp + ((size_t)p << 9) + k0);
                const float4 bhi = *(const float4*)(Bp + ((size_t)p << 9) + k0 + 4);
                uint4 o;
                o.x = bf2pack(fmaxf(alo.x - blo.x, 0.f), fmaxf(alo.y - blo.y, 0.f));
                o.y = bf2pack(fmaxf(alo.z - blo.z, 0.f), fmaxf(alo.w - blo.w, 0.f));
                o.z = bf2pack(fmaxf(ahi.x - bhi.x, 0.f), fmaxf(ahi.y - bhi.y, 0.f));
                o.w = bf2pack(fmaxf(ahi.z - bhi.z, 0.f), fmaxf(ahi.w - bhi.w, 0.f));
                *(uint4*)(As + (r << 6) + swz) = o;
            }
            __syncthreads();
#pragma unroll
            for (int kk = 0; kk < 2; ++kk) {
                const int ck = (kk << 2) + quad;
                const int po = (ck ^ (l16 & 7)) << 3;
                bf16x8 af[4], wf[8];
#pragma unroll
                for (int tm = 0; tm < 4; ++tm) {
                    const int row = (wm << 6) + (tm << 4) + l16;
                    af[tm] = *(const bf16x8*)(As + (row << 6) + po);
                }
#pragma unroll
                for (int tn = 0; tn < 8; ++tn) {
                    const int wrow = (wn << 7) + (tn << 4) + l16;
                    wf[tn] = *(const bf16x8*)(Ws + (wrow << 6) + ((ck ^ (wrow & 7)) << 3));
                }
#pragma unroll
                for (int tm = 0; tm < 4; ++tm)
#pragma unroll
                    for (int tn = 0; tn < 8; ++tn)
                        acc[tm][tn] = __builtin_amdgcn_mfma_f32_16x16x32_bf16(
                            af[tm], wf[tn], acc[tm][tn], 0, 0, 0);
            }
            __syncthreads();
        }
        // epilogue (registers only -> no extra barrier needed before next cs)
#pragma unroll
        for (int tn = 0; tn < 8; ++tn) {
            const int col = N0 + (wn << 7) + (tn << 4) + l16;
            float wsum = 0.f, wsq = 0.f;
#pragma unroll
            for (int gp = 0; gp < 2; ++gp) {
                float vmax = -3.4e38f, vmin = 3.4e38f, vs = 0.f, vq = 0.f;
#pragma unroll
                for (int tm = gp * 2; tm < gp * 2 + 2; ++tm)
#pragma unroll
                    for (int r = 0; r < 4; ++r) {
                        const float v = acc[tm][tn][r];
                        vmax = fmaxf(vmax, v);
                        vmin = fminf(vmin, v);
                        vs += v;
                        vq += v * v;
                    }
#pragma unroll
                for (int off = 16; off < 64; off <<= 1) {
                    vmax = fmaxf(vmax, __shfl_xor(vmax, off));
                    vmin = fminf(vmin, __shfl_xor(vmin, off));
                    vs += __shfl_xor(vs, off);
                    vq += __shfl_xor(vq, off);
                }
                if (quad == 0) {
                    const int kg = s2 * 32 + pedb + (wm << 1) + gp;
                    maxv[(size_t)kg * 1024 + col] = vmax;
                    minv[(size_t)kg * 1024 + col] = vmin;
                }
                wsum += vs;
                wsq += vq;
            }
            if (quad == 0) {
                const int slot = (s2 << 4) + (rb << 1) + wm;  // 16 per scene
                psum[(size_t)slot * 1024 + col] = wsum;
                psumsq[(size_t)slot * 1024 + col] = wsq;
            }
        }
    }
}

// BN2 + relu for one (scene, col-quarter), 256 threads.
__device__ void final_unit_256(int u, int tid,
                               const float* __restrict__ maxv, const float* __restrict__ minv,
                               const float* __restrict__ psum, const float* __restrict__ psumsq,
                               const float* __restrict__ g2, const float* __restrict__ be2,
                               float* __restrict__ out) {
    const int s3 = u >> 2;
    const int c = ((u & 3) << 8) + tid;
    float sm = 0.f, sq = 0.f;
#pragma unroll
    for (int t = 0; t < 16; ++t) {
        sm += psum[(size_t)(s3 * 16 + t) * 1024 + c];
        sq += psumsq[(size_t)(s3 * 16 + t) * 1024 + c];
    }
    const float mu = sm * (1.f / 1024.f);
    const float var = sq * (1.f / 1024.f) - mu * mu;
    const float inv = rsqrtf(var + EPS_);
    const float scale = g2[c] * inv;
    const float bb = be2[c];
    const float* src = (scale >= 0.f) ? maxv : minv;
    for (int k = 0; k < 32; ++k) {
        const float v = src[(size_t)(s3 * 32 + k) * 1024 + c];
        out[(size_t)(s3 * 32 + k) * 1024 + c] = fmaxf((v - mu) * scale + bb, 0.f);
    }
}

// ============================================================================
// Cooperative single kernel (grid-stride, works at any grid size)
// ============================================================================
__global__ __launch_bounds__(256, 2)
void k_all(const float* __restrict__ pos, const float* __restrict__ h,
           const float* __restrict__ We, const float* __restrict__ W1,
           const float* __restrict__ g1, const float* __restrict__ be1,
           const float* __restrict__ W2, const float* __restrict__ g2,
           const float* __restrict__ be2,
           float* __restrict__ A, float* __restrict__ Bv, u16* __restrict__ w2t,
           float* __restrict__ maxv, float* __restrict__ minv,
           float* __restrict__ psum, float* __restrict__ psumsq,
           float* __restrict__ out) {
    __shared__ __align__(16) char smem_raw[49152];
    cg::grid_group grid = cg::this_grid();
    const int b = blockIdx.x;
    const int g = gridDim.x;
    const int tid = threadIdx.x;

    // phase 1: 384 units (256 scene-prep + 128 W2-transpose)
    for (int u = b; u < 384; u += g) {
        if (u < 256)
            prep_scene_256(u, tid, (float*)smem_raw, pos, h, We, W1, g1, be1, A, Bv);
        else
            w2t_tile_256(u - 256, tid, smem_raw, W2, w2t);
        __syncthreads();  // smem reuse across units
    }
    __threadfence();
    grid.sync();

    // phase 2: 512 M-tiles
    {
        u16* As = (u16*)smem_raw;
        u16* Ws = (u16*)(smem_raw + 16384);
        for (int mt = b; mt < 512; mt += g)
            gemm_mtile(mt, tid, As, Ws, A, Bv, w2t, maxv, minv, psum, psumsq);
    }
    __threadfence();
    grid.sync();

    // phase 3: 256 units
    for (int u = b; u < 256; u += g)
        final_unit_256(u, tid, maxv, minv, psum, psumsq, g2, be2, out);
}

// ============================================================================
// Fallback path: R5-proven 3 kernels
// ============================================================================
__global__ __launch_bounds__(256)
void k_prep_fb(const float* __restrict__ pos, const float* __restrict__ h,
               const float* __restrict__ We, const float* __restrict__ W1,
               const float* __restrict__ g1, const float* __restrict__ be1,
               const float* __restrict__ W2,
               float* __restrict__ A, float* __restrict__ Bv, u16* __restrict__ w2t) {
    __shared__ __align__(16) char smem_raw[16912];
    const int bid = blockIdx.x;
    if (bid < 256)
        prep_scene_256(bid, threadIdx.x, (float*)smem_raw, pos, h, We, W1, g1, be1, A, Bv);
    else
        w2t_tile_256(bid - 256, threadIdx.x, smem_raw, W2, w2t);
}

__global__ __launch_bounds__(256, 2)
void k_gemm_fb(const float* __restrict__ A, const float* __restrict__ Bv,
               const u16* __restrict__ w2t,
               float* __restrict__ maxv, float* __restrict__ minv,
               float* __restrict__ psum, float* __restrict__ psumsq) {
    __shared__ __align__(16) char smem_raw[49152];
    gemm_mtile(blockIdx.x, threadIdx.x, (u16*)smem_raw, (u16*)(smem_raw + 16384),
               A, Bv, w2t, maxv, minv, psum, psumsq);
}

__global__ void k_final_fb(const float* __restrict__ maxv, const float* __restrict__ minv,
                           const float* __restrict__ psum, const float* __restrict__ psumsq,
                           const float* __restrict__ g2, const float* __restrict__ be2,
                           float* __restrict__ out) {
    final_unit_256(blockIdx.x, threadIdx.x, maxv, minv, psum, psumsq, g2, be2, out);
}

extern "C" void kernel_launch(void* const* d_in, const int* in_sizes, int n_in,
                              void* d_out, int out_size, void* d_ws, size_t ws_size,
                              hipStream_t stream) {
    const float* h_states = (const float*)d_in[0];
    const float* end_pos = (const float*)d_in[2];
    const float* W_embed = (const float*)d_in[4];
    const float* W1 = (const float*)d_in[6];
    const float* g1 = (const float*)d_in[8];
    const float* be1 = (const float*)d_in[9];
    const float* W2 = (const float*)d_in[10];
    const float* g2 = (const float*)d_in[12];
    const float* be2 = (const float*)d_in[13];
    float* out = (float*)d_out;

    float* Abuf = (float*)d_ws;                // 1,048,576 f
    float* Bbuf = Abuf + 1048576;              // 1,048,576 f
    float* maxv = Bbuf + 1048576;              // 2,097,152 f
    float* minv = maxv + 2097152;              // 2,097,152 f
    float* psum = minv + 2097152;              // 1,048,576 f
    float* psumsq = psum + 1048576;            // 1,048,576 f
    u16* w2t = (u16*)(psumsq + 1048576);       // 524,288 u16

    // Decide coop grid from the runtime's own occupancy model (what the
    // cooperative-launch validator checks against). Host-side queries only —
    // no stream ops, graph-capture safe.
    int coop_ok = 0, occ = 0, ncu = 0, dev = 0;
    hipGetDevice(&dev);
    hipDeviceGetAttribute(&coop_ok, hipDeviceAttributeCooperativeLaunch, dev);
    hipDeviceGetAttribute(&ncu, hipDeviceAttributeMultiprocessorCount, dev);
    hipOccupancyMaxActiveBlocksPerMultiprocessor(&occ, (const void*)k_all, 256, 0);
    int grid = occ * ncu;
    if (grid > 512) grid = 512;

    if (coop_ok && grid >= 64) {
        void* args[] = {
            (void*)&end_pos, (void*)&h_states, (void*)&W_embed, (void*)&W1,
            (void*)&g1, (void*)&be1, (void*)&W2, (void*)&g2, (void*)&be2,
            (void*)&Abuf, (void*)&Bbuf, (void*)&w2t,
            (void*)&maxv, (void*)&minv, (void*)&psum, (void*)&psumsq, (void*)&out
        };
        hipError_t e = hipLaunchCooperativeKernel((void*)k_all, dim3(grid), dim3(256),
                                                  args, 0, stream);
        if (e == hipSuccess) return;
    }
    // fallback: proven 3-kernel path
    k_prep_fb<<<dim3(384), dim3(256), 0, stream>>>(end_pos, h_states, W_embed, W1,
                                                   g1, be1, W2, Abuf, Bbuf, w2t);
    k_gemm_fb<<<dim3(512), dim3(256), 0, stream>>>(Abuf, Bbuf, w2t, maxv, minv, psum, psumsq);
    k_final_fb<<<dim3(256), dim3(256), 0, stream>>>(maxv, minv, psum, psumsq, g2, be2, out);
}

// Round 10
// 183.900 us; speedup vs baseline: 2.3899x; 2.3899x over previous
//
#include <hip/hip_runtime.h>
#include <hip/hip_bf16.h>

#define S_ 64
#define P_ 32
#define N_ 2048
#define H_ 64
#define E_ 64
#define D1_ 512
#define D2_ 1024
#define EPS_ 1e-5f

typedef unsigned short u16;
using bf16x8 = __attribute__((ext_vector_type(8))) __bf16;
using floatx4 = __attribute__((ext_vector_type(4))) float;

__device__ inline u16 f2bf(float x) {
    unsigned u = __float_as_uint(x);
    unsigned r = (u + 0x7fffu + ((u >> 16) & 1u)) >> 16;
    return (u16)r;
}

// ============================================================================
// Device helpers (logic verified on HW in round 9)
// ============================================================================

// Scene prep for one (scene, d-quarter), 256 threads. Writes BN1'd A/B factors.
__device__ void prep_scene_256(int u, int tid, float* smem,
                               const float* __restrict__ pos, const float* __restrict__ h,
                               const float* __restrict__ We, const float* __restrict__ W1,
                               const float* __restrict__ g1, const float* __restrict__ be1,
                               float* __restrict__ A, float* __restrict__ Bv) {
    const int s = u >> 2, dq = u & 3;
    const int jg = tid >> 7, dl = tid & 127;   // 2 j-groups x 128 channels
    const int d = (dq << 7) + dl;
    float* hs = smem;           // 2048: h[j][e]
    float* ps = smem + 2048;    // 64: pos
    float* red = smem + 2112;   // 1024: 4 stats x 256 threads
    for (int i = tid; i < 2048; i += 256) hs[i] = h[(size_t)s * 2048 + i];
    if (tid < 64) ps[tid] = pos[s * 64 + tid];
    __syncthreads();
    float wq0 = 0.f, wq1 = 0.f;
    for (int e = 0; e < 64; ++e) {
        const float wv = W1[e * 512 + d];
        wq0 += We[e] * wv;
        wq1 += We[64 + e] * wv;
    }
    float w[16], uu[16];
#pragma unroll
    for (int jj = 0; jj < 16; ++jj) w[jj] = 0.f;
    const float4* h4 = (const float4*)hs;
    for (int e4 = 0; e4 < 16; ++e4) {
        const float c0 = W1[(64 + e4 * 4 + 0) * 512 + d];
        const float c1 = W1[(64 + e4 * 4 + 1) * 512 + d];
        const float c2 = W1[(64 + e4 * 4 + 2) * 512 + d];
        const float c3 = W1[(64 + e4 * 4 + 3) * 512 + d];
#pragma unroll
        for (int jj = 0; jj < 16; ++jj) {
            const float4 hv = h4[((jg << 4) + jj) * 16 + e4];
            w[jj] += hv.x * c0 + hv.y * c1 + hv.z * c2 + hv.w * c3;
        }
    }
    float sw = 0.f, sww = 0.f, su = 0.f, suu = 0.f;
#pragma unroll
    for (int jj = 0; jj < 16; ++jj) {
        const int j = (jg << 4) + jj;
        uu[jj] = ps[2 * j] * wq0 + ps[2 * j + 1] * wq1;
        w[jj] += uu[jj];
        sw += w[jj]; sww += w[jj] * w[jj];
        su += uu[jj]; suu += uu[jj] * uu[jj];
    }
    red[(jg << 7) + dl] = sw;
    red[256 + (jg << 7) + dl] = sww;
    red[512 + (jg << 7) + dl] = su;
    red[768 + (jg << 7) + dl] = suu;
    __syncthreads();
    const float tw = red[dl] + red[128 + dl];
    const float tww = red[256 + dl] + red[384 + dl];
    const float tu = red[512 + dl] + red[640 + dl];
    const float tuu = red[768 + dl] + red[896 + dl];
    const float mw = tw * (1.f / 32.f), mu2 = tu * (1.f / 32.f);
    const float var = (tww * (1.f / 32.f) - mw * mw) + (tuu * (1.f / 32.f) - mu2 * mu2);
    const float sc = rsqrtf(var + EPS_) * g1[d];
    const float bb = be1[d];
#pragma unroll
    for (int jj = 0; jj < 16; ++jj) {
        const int j = (jg << 4) + jj;
        A[(size_t)(s * 32 + j) * 512 + d] = (w[jj] - mw) * sc + bb;
        Bv[(size_t)(s * 32 + j) * 512 + d] = (uu[jj] - mu2) * sc;
    }
}

// W2 transpose+bf16 for one 64x64 tile, 256 threads.
__device__ void w2t_tile_256(int b2, int tid, void* smem,
                             const float* __restrict__ W2, u16* __restrict__ w2t) {
    float (*tile)[65] = (float (*)[65])smem;  // 16.6 KB
    const int bi = b2 & 15, bj = b2 >> 4;     // 16 n-tiles x 8 k-tiles
    const int tx = tid & 63, ty = tid >> 6;   // 64 x 4
#pragma unroll
    for (int i = 0; i < 64; i += 4)
        tile[ty + i][tx] = W2[(size_t)(bj * 64 + ty + i) * 1024 + bi * 64 + tx];
    __syncthreads();
#pragma unroll
    for (int i = 0; i < 64; i += 4)
        w2t[(size_t)(bi * 64 + ty + i) * 512 + bj * 64 + tx] = f2bf(tile[tx][ty + i]);
}

// ============================================================================
// Fused GEMM: block = one M-tile (128 rows = 4 peds x 32 j), loops 4 col-splits
// of 256. As (x1 K-slice) built in LDS with native bf16 converts (gfx950
// v_cvt_pk path); Ws staged via global_load_lds. R5-proven swizzles.
// ============================================================================
__global__ __launch_bounds__(256, 2)
void k_gemm(const float* __restrict__ A, const float* __restrict__ Bv,
            const u16* __restrict__ w2t,
            float* __restrict__ maxv, float* __restrict__ minv,
            float* __restrict__ psum, float* __restrict__ psumsq) {
    __shared__ __align__(16) u16 As[128 * 64];   // 16 KB
    __shared__ __align__(16) u16 Ws[256 * 64];   // 32 KB
    const int tid = threadIdx.x;
    const int wave = tid >> 6, lane = tid & 63;
    const int wm = wave >> 1, wn = wave & 1;
    const int quad = lane >> 4, l16 = lane & 15;
    const int lrow = lane >> 3, lchk = lane & 7;
    const int gchk = lchk ^ lrow;
    const int sj = tid >> 3, sc8 = tid & 7;
    const int mt = blockIdx.x;
    const int s2 = mt >> 3, rb = mt & 7;
    const int pedb = rb << 2;
    const float* Aj = A + ((size_t)(s2 * 32 + sj) << 9) + (sc8 << 3);
    const float* Bp = Bv + ((size_t)(s2 * 32 + pedb) << 9) + (sc8 << 3);
    const int swz = (sc8 ^ (sj & 7)) << 3;

    for (int cs = 0; cs < 4; ++cs) {
        const int N0 = cs << 8;
        floatx4 acc[4][8] = {};
        for (int it = 0; it < 8; ++it) {
            const int k0 = it << 6;
            // stage Ws: 256 rows x 64 k via global_load_lds
#pragma unroll
            for (int t = 0; t < 8; ++t) {
                const int rbase = (wave << 6) + (t << 3);
                const u16* gb = w2t + (size_t)(N0 + rbase + lrow) * 512 + (k0 + (gchk << 3));
                __builtin_amdgcn_global_load_lds(
                    (const __attribute__((address_space(1))) void*)gb,
                    (__attribute__((address_space(3))) void*)(Ws + (rbase << 6)), 16, 0, 0);
            }
            // stage As: 128 rows (4 peds x 32 j) x 64 k, per-lane relu-diff.
            // Native (__bf16) casts -> v_cvt_pk_bf16_f32 on gfx950 (4x fewer
            // VALU ops than manual round-pack; numerics identical, R3/R7).
            {
                const float4 alo = *(const float4*)(Aj + k0);
                const float4 ahi = *(const float4*)(Aj + k0 + 4);
#pragma unroll
                for (int p = 0; p < 4; ++p) {
                    const int r = (p << 5) + sj;
                    const float4 blo = *(const float4*)(Bp + ((size_t)p << 9) + k0);
                    const float4 bhi = *(const float4*)(Bp + ((size_t)p << 9) + k0 + 4);
                    bf16x8 o;
                    o[0] = (__bf16)fmaxf(alo.x - blo.x, 0.f);
                    o[1] = (__bf16)fmaxf(alo.y - blo.y, 0.f);
                    o[2] = (__bf16)fmaxf(alo.z - blo.z, 0.f);
                    o[3] = (__bf16)fmaxf(alo.w - blo.w, 0.f);
                    o[4] = (__bf16)fmaxf(ahi.x - bhi.x, 0.f);
                    o[5] = (__bf16)fmaxf(ahi.y - bhi.y, 0.f);
                    o[6] = (__bf16)fmaxf(ahi.z - bhi.z, 0.f);
                    o[7] = (__bf16)fmaxf(ahi.w - bhi.w, 0.f);
                    *(bf16x8*)(As + (r << 6) + swz) = o;
                }
            }
            __syncthreads();
#pragma unroll
            for (int kk = 0; kk < 2; ++kk) {
                const int ck = (kk << 2) + quad;
                const int po = (ck ^ (l16 & 7)) << 3;
                bf16x8 af[4], wf[8];
#pragma unroll
                for (int tm = 0; tm < 4; ++tm) {
                    const int row = (wm << 6) + (tm << 4) + l16;
                    af[tm] = *(const bf16x8*)(As + (row << 6) + po);
                }
#pragma unroll
                for (int tn = 0; tn < 8; ++tn) {
                    const int wrow = (wn << 7) + (tn << 4) + l16;
                    wf[tn] = *(const bf16x8*)(Ws + (wrow << 6) + ((ck ^ (wrow & 7)) << 3));
                }
#pragma unroll
                for (int tm = 0; tm < 4; ++tm)
#pragma unroll
                    for (int tn = 0; tn < 8; ++tn)
                        acc[tm][tn] = __builtin_amdgcn_mfma_f32_16x16x32_bf16(
                            af[tm], wf[tn], acc[tm][tn], 0, 0, 0);
            }
            __syncthreads();
        }
        // epilogue: j-max/min per ped + BN2 partial sums (registers only)
#pragma unroll
        for (int tn = 0; tn < 8; ++tn) {
            const int col = N0 + (wn << 7) + (tn << 4) + l16;
            float wsum = 0.f, wsq = 0.f;
#pragma unroll
            for (int gp = 0; gp < 2; ++gp) {
                float vmax = -3.4e38f, vmin = 3.4e38f, vs = 0.f, vq = 0.f;
#pragma unroll
                for (int tm = gp * 2; tm < gp * 2 + 2; ++tm)
#pragma unroll
                    for (int r = 0; r < 4; ++r) {
                        const float v = acc[tm][tn][r];
                        vmax = fmaxf(vmax, v);
                        vmin = fminf(vmin, v);
                        vs += v;
                        vq += v * v;
                    }
#pragma unroll
                for (int off = 16; off < 64; off <<= 1) {
                    vmax = fmaxf(vmax, __shfl_xor(vmax, off));
                    vmin = fminf(vmin, __shfl_xor(vmin, off));
                    vs += __shfl_xor(vs, off);
                    vq += __shfl_xor(vq, off);
                }
                if (quad == 0) {
                    const int kg = s2 * 32 + pedb + (wm << 1) + gp;
                    maxv[(size_t)kg * 1024 + col] = vmax;
                    minv[(size_t)kg * 1024 + col] = vmin;
                }
                wsum += vs;
                wsq += vq;
            }
            if (quad == 0) {
                const int slot = (s2 << 4) + (rb << 1) + wm;  // 16 per scene
                psum[(size_t)slot * 1024 + col] = wsum;
                psumsq[(size_t)slot * 1024 + col] = wsq;
            }
        }
    }
}

// ============================================================================
// Prep / final kernels
// ============================================================================
__global__ __launch_bounds__(256)
void k_prep(const float* __restrict__ pos, const float* __restrict__ h,
            const float* __restrict__ We, const float* __restrict__ W1,
            const float* __restrict__ g1, const float* __restrict__ be1,
            const float* __restrict__ W2,
            float* __restrict__ A, float* __restrict__ Bv, u16* __restrict__ w2t) {
    __shared__ __align__(16) char smem_raw[16912];
    const int bid = blockIdx.x;
    if (bid < 256)
        prep_scene_256(bid, threadIdx.x, (float*)smem_raw, pos, h, We, W1, g1, be1, A, Bv);
    else
        w2t_tile_256(bid - 256, threadIdx.x, smem_raw, W2, w2t);
}

__global__ __launch_bounds__(256)
void k_final(const float* __restrict__ maxv, const float* __restrict__ minv,
             const float* __restrict__ psum, const float* __restrict__ psumsq,
             const float* __restrict__ g2, const float* __restrict__ be2,
             float* __restrict__ out) {
    const int u = blockIdx.x, tid = threadIdx.x;
    const int s3 = u >> 2;
    const int c = ((u & 3) << 8) + tid;
    float sm = 0.f, sq = 0.f;
#pragma unroll
    for (int t = 0; t < 16; ++t) {
        sm += psum[(size_t)(s3 * 16 + t) * 1024 + c];
        sq += psumsq[(size_t)(s3 * 16 + t) * 1024 + c];
    }
    const float mu = sm * (1.f / 1024.f);
    const float var = sq * (1.f / 1024.f) - mu * mu;
    const float inv = rsqrtf(var + EPS_);
    const float scale = g2[c] * inv;
    const float bb = be2[c];
    const float* src = (scale >= 0.f) ? maxv : minv;  // BN monotone direction
    for (int k = 0; k < 32; ++k) {
        const float v = src[(size_t)(s3 * 32 + k) * 1024 + c];
        out[(size_t)(s3 * 32 + k) * 1024 + c] = fmaxf((v - mu) * scale + bb, 0.f);
    }
}

extern "C" void kernel_launch(void* const* d_in, const int* in_sizes, int n_in,
                              void* d_out, int out_size, void* d_ws, size_t ws_size,
                              hipStream_t stream) {
    const float* h_states = (const float*)d_in[0];
    const float* end_pos = (const float*)d_in[2];
    const float* W_embed = (const float*)d_in[4];
    const float* W1 = (const float*)d_in[6];
    const float* g1 = (const float*)d_in[8];
    const float* be1 = (const float*)d_in[9];
    const float* W2 = (const float*)d_in[10];
    const float* g2 = (const float*)d_in[12];
    const float* be2 = (const float*)d_in[13];
    float* out = (float*)d_out;

    float* Abuf = (float*)d_ws;                // 1,048,576 f
    float* Bbuf = Abuf + 1048576;              // 1,048,576 f
    float* maxv = Bbuf + 1048576;              // 2,097,152 f
    float* minv = maxv + 2097152;              // 2,097,152 f
    float* psum = minv + 2097152;              // 1,048,576 f
    float* psumsq = psum + 1048576;            // 1,048,576 f
    u16* w2t = (u16*)(psumsq + 1048576);       // 524,288 u16

    k_prep<<<dim3(384), dim3(256), 0, stream>>>(end_pos, h_states, W_embed, W1,
                                                g1, be1, W2, Abuf, Bbuf, w2t);
    k_gemm<<<dim3(512), dim3(256), 0, stream>>>(Abuf, Bbuf, w2t, maxv, minv, psum, psumsq);
    k_final<<<dim3(256), dim3(256), 0, stream>>>(maxv, minv, psum, psumsq, g2, be2, out);
}